// Round 12
// baseline (270.026 us; speedup 1.0000x reference)
//
#include <hip/hip_runtime.h>
#include <hip/hip_fp16.h>
#include <math.h>

// Problem constants
#define BB 4
#define HH 48
#define WW 48
#define DD 64
#define CH 46
#define CC (CH*CH)       // 2116
#define HWp (HH*WW)      // 2304
#define PW 50            // zero-padded field width
#define PP (PW*PW)       // 2500 padded pixels
#define UST 2512         // U row stride (halves), 16B-mult
#define CAST 2120        // CA row stride (halves), 16B-mult
#define QN 2304          // Wgt cols = bg positions = acl-GEMM K
#define NSPL 8           // acl split-K chunks
#define KCH (QN/NSPL)    // 288 = 9 BK-32 iters

typedef __attribute__((ext_vector_type(8))) short short8;
typedef __attribute__((ext_vector_type(4))) float float4v;

// ---------- workspace layout (byte offsets, all 16B-aligned) ----------
#define OFFB_GPAD  ((size_t)0)            // bf16 [B][2500][64]     1,280,000 B
#define OFFB_BGPAD ((size_t)1280000)      // bf16 [B][2500][64]     1,280,000 B
#define OFFB_E     ((size_t)2560000)      // f32  [B][2304]            36,864 B
#define OFFB_K1D   ((size_t)2596864)      // f32  [B][CC]              33,856 B
#define OFFB_BGT   ((size_t)2630720)      // bf16 [B][64][2304]     1,179,648 B
#define OFFB_U     ((size_t)3810368)      // fp16 [B][2500][UST]   50,240,000 B
#define OFFB_CA    ((size_t)54050368)     // bf16 [B][2304][CAST]  39,075,840 B
#define OFFB_WGT   ((size_t)93126208)     // bf16 [B][2304][2304]  42,467,328 B
#define OFFB_ACLP  ((size_t)135593536)    // fp16 [NSPL][B][2304][64] 9,437,184 B
// total 145,030,720 B

// ---------- helpers ----------
__device__ __forceinline__ ushort f2bf(float x) {
    unsigned u = __float_as_uint(x);
    return (ushort)((u + 0x7FFFu + ((u >> 16) & 1u)) >> 16);
}
__device__ __forceinline__ float bf2f(ushort h) {
    return __uint_as_float((unsigned)h << 16);
}

__device__ __forceinline__ float waveReduceSum(float x) {
#pragma unroll
    for (int o = 32; o > 0; o >>= 1) x += __shfl_down(x, o, 64);
    return x;
}

__device__ __forceinline__ float blockReduceSum(float x, float* sm) {
#pragma unroll
    for (int o = 32; o > 0; o >>= 1) x += __shfl_down(x, o, 64);
    int lane = threadIdx.x & 63, w = threadIdx.x >> 6;
    __syncthreads();
    if (lane == 0) sm[w] = x;
    __syncthreads();
    return sm[0] + sm[1] + sm[2] + sm[3];
}

// fast tanh via hardware exp: tanh(z) = 1 - 2/(e^{2z}+1)
__device__ __forceinline__ float fast_tanh(float z) {
    float e = __expf(2.f * z);
    return 1.f - 2.f / (e + 1.f);
}

// async 16B global->LDS (wave-uniform LDS base + lane*16)
typedef __attribute__((address_space(3))) void lds_void_t;
typedef __attribute__((address_space(1))) void gmem_void_t;
__device__ __forceinline__ void gld16(const ushort* g, ushort* lds) {
    __builtin_amdgcn_global_load_lds((gmem_void_t*)g, (lds_void_t*)lds, 16, 0, 0);
}

// ---------- build padded fields: gpad = bf16(g), bgpad = bf16(g*mask), e = sum_c bg^2 ----------
__global__ __launch_bounds__(256) void build_pads(const float* __restrict__ g,
                                                  const float* __restrict__ mask,
                                                  ushort* __restrict__ gpad,
                                                  ushort* __restrict__ bgpad,
                                                  float* __restrict__ e) {
    int w = threadIdx.x >> 6, c = threadIdx.x & 63;
    int q4 = blockIdx.x * 4 + w;         // [0, B*2500)
    int b = q4 / PP, q = q4 % PP;
    int yp = q / PW, xp = q % PW;
    size_t o = (size_t)q4 * DD + c;
    if (yp >= 1 && yp <= HH && xp >= 1 && xp <= WW) {
        int pix = (yp - 1) * WW + (xp - 1);
        float gv = g[((size_t)b * HWp + pix) * DD + c];
        float m  = mask[(size_t)b * HWp + pix];
        float bgv = gv * m;
        gpad[o]  = f2bf(gv);
        bgpad[o] = f2bf(bgv);
        float ss = waveReduceSum(bgv * bgv);
        if (c == 0) e[b * HWp + pix] = ss;
    } else {
        gpad[o] = 0;
        bgpad[o] = 0;
    }
}

// ---------- bgT transpose (interior bg [2304 pix][64ch] -> [64][2304]) + k1d ----------
// blocks [0,144): transpose tiles; [144, 144+34): k1d 3x3 window sums of e.
__global__ __launch_bounds__(256) void build_bgt_k1d(const ushort* __restrict__ bgpad,
                                                     const float* __restrict__ e,
                                                     ushort* __restrict__ bgT,
                                                     float* __restrict__ k1d) {
    int t = threadIdx.x;
    if (blockIdx.x < 144) {
        int b = blockIdx.x / 36, tile = blockIdx.x % 36;
        __shared__ ushort T[64 * 65];
        const ushort* src = bgpad + (size_t)b * PP * DD;
        int lr = t >> 3, c8 = (t & 7) * 8;
#pragma unroll
        for (int pass = 0; pass < 2; pass++) {
            int r = lr + pass * 32;          // pixel within tile
            int p = tile * 64 + r;           // [0,2304)
            int py = p / 48 + 1, px = p % 48 + 1;
            uint4 d = *(const uint4*)(src + (size_t)(py * PW + px) * DD + c8);
            ushort tmp[8];
            *(uint4*)tmp = d;
#pragma unroll
            for (int u = 0; u < 8; u++) T[r * 65 + c8 + u] = tmp[u];
        }
        __syncthreads();
        ushort* dst = bgT + (size_t)b * DD * QN;
#pragma unroll
        for (int pass = 0; pass < 2; pass++) {
            int c = lr + pass * 32;          // channel
            int j8 = (t & 7) * 8;
            ushort tmp[8];
#pragma unroll
            for (int u = 0; u < 8; u++) tmp[u] = T[(j8 + u) * 65 + c];
            *(uint4*)(dst + (size_t)c * QN + tile * 64 + j8) = *(const uint4*)tmp;
        }
    } else {
        int jg = (blockIdx.x - 144) * 256 + t;
        if (jg < BB * CC) {
            int b = jg / CC, j = jg % CC;
            int jy = j / CH, jx = j - jy * CH;
            const float* eb = e + b * HWp + jy * WW + jx;
            float s = 0.f;
#pragma unroll
            for (int dy = 0; dy < 3; dy++)
#pragma unroll
                for (int dx = 0; dx < 3; dx++) s += eb[dy * WW + dx];
            k1d[jg] = s;
        }
    }
}

// ---------- U-GEMM: U[p][q] = sum_c gpad[p,c]*bgpad[q,c], fp16, K=64 single shot ----------
// 128x128 tiles, flat 1600-block grid (8x200), batch = XCD-pair. 3-bit XOR swizzle
// (R6-verified conflict-free): store chunk (l&7)^(sr&7), read ((h*4+quad)^(l15&7)).
__global__ __launch_bounds__(256) void ugemm(const ushort* __restrict__ gpad,
                                             const ushort* __restrict__ bgpad,
                                             __half* __restrict__ U) {
    __shared__ ushort As[128 * 64];
    __shared__ ushort Bs[128 * 64];
    int i0 = blockIdx.x;
    int b = (i0 & 7) >> 1;
    int tile = ((i0 >> 3) << 1) | (i0 & 1);   // 0..399
    int ty = tile / 20, tx = tile - ty * 20;
    int p0 = ty * 128, q0 = tx * 128;
    const ushort* Ag = gpad + (size_t)b * PP * DD;
    const ushort* Bg = bgpad + (size_t)b * PP * DD;

    int tid = threadIdx.x;
    int l = tid & 63, w = tid >> 6;
    int quad = l >> 4, l15 = l & 15;
    int sw = l15 & 7;
    int wm = (w >> 1) * 64, wn = (w & 1) * 64;
    int sr = l >> 3;                          // row in 8-row staging group
    int gch = (l & 7) ^ (sr & 7);             // swizzled global 16B chunk

#pragma unroll
    for (int i = 0; i < 4; i++) {
        int rg = 4 * w + i;
        int r = rg * 8 + sr;
        if (p0 + r < PP) gld16(Ag + (size_t)(p0 + r) * DD + gch * 8, As + rg * 512);
        if (q0 + r < PP) gld16(Bg + (size_t)(q0 + r) * DD + gch * 8, Bs + rg * 512);
    }
    __syncthreads();

    float4v acc[4][4];
#pragma unroll
    for (int i = 0; i < 4; i++)
#pragma unroll
        for (int j = 0; j < 4; j++) acc[i][j] = (float4v){0.f, 0.f, 0.f, 0.f};

#pragma unroll
    for (int h = 0; h < 2; h++) {
        short8 af[4], bf[4];
#pragma unroll
        for (int i = 0; i < 4; i++)
            af[i] = *(const short8*)&As[(wm + i * 16 + l15) * 64 + ((h * 4 + quad) ^ sw) * 8];
#pragma unroll
        for (int j = 0; j < 4; j++)
            bf[j] = *(const short8*)&Bs[(wn + j * 16 + l15) * 64 + ((h * 4 + quad) ^ sw) * 8];
#pragma unroll
        for (int i = 0; i < 4; i++)
#pragma unroll
            for (int j = 0; j < 4; j++)
                acc[i][j] = __builtin_amdgcn_mfma_f32_16x16x32_bf16(af[i], bf[j], acc[i][j], 0, 0, 0);
    }

    __half* Ub = U + (size_t)b * PP * UST;
#pragma unroll
    for (int i = 0; i < 4; i++) {
#pragma unroll
        for (int j = 0; j < 4; j++) {
            int n = q0 + wn + j * 16 + l15;
            if (n < PP) {
#pragma unroll
                for (int r = 0; r < 4; r++) {
                    int m = p0 + wm + i * 16 + quad * 4 + r;
                    if (m < PP) Ub[(size_t)m * UST + n] = __float2half(acc[i][j][r]);
                }
            }
        }
    }
}

// ---------- fused CS-gather + standardize + tanh + softmax -> bf16 CA ----------
// CS[m][j] = sum_s U[base_m+off_s][base_j+off_s], 9 diagonal taps.
// One block per (b,m); 9216 blocks (b = (i0&7)>>1 for XCD-pair locality).
__global__ __launch_bounds__(256) void cs_softmax(const __half* __restrict__ U,
                                                  const float* __restrict__ k1d,
                                                  ushort* __restrict__ CA) {
    __shared__ float sm[4];
    int i0 = blockIdx.x;
    int b = (i0 & 7) >> 1;
    int m = ((i0 >> 3) << 1) | (i0 & 1);      // 0..2303
    int y = m / 48, x = m - y * 48;
    const __half* Ub = U + (size_t)b * PP * UST;
    const float* k1 = k1d + b * CC;
    const __half* rows[9];
#pragma unroll
    for (int dy = 0; dy < 3; dy++)
#pragma unroll
        for (int dx = 0; dx < 3; dx++)
            rows[dy * 3 + dx] = Ub + (size_t)((y + dy) * PW + (x + dx)) * UST;

    int t = threadIdx.x;
    float v[9];
#pragma unroll
    for (int i = 0; i < 9; i++) {
        int j = t + i * 256;
        if (j < CC) {
            int jy = j / CH, jx = j - jy * CH;
            int base = (jy + 1) * PW + (jx + 1);
            float cs = 0.f;
#pragma unroll
            for (int s = 0; s < 9; s++) {
                int off = (s / 3) * PW + (s % 3);
                cs += __half2float(rows[s][base + off]);
            }
            v[i] = k1[j] - 2.f * cs;
        } else v[i] = 0.f;
    }
    float s0 = 0.f;
#pragma unroll
    for (int i = 0; i < 9; i++) { int j = t + i * 256; if (j < CC) s0 += v[i]; }
    s0 = blockReduceSum(s0, sm);
    float mu = s0 / (float)CC;
    float vs = 0.f;
#pragma unroll
    for (int i = 0; i < 9; i++) {
        int j = t + i * 256;
        if (j < CC) { float d = v[i] - mu; vs += d * d; }
    }
    vs = blockReduceSum(vs, sm);
    float inv_sd = 1.f / sqrtf(vs / (float)CC);
    // logits bounded in [-50,50]: exp without max-subtraction cannot overflow fp32
    float es = 0.f;
#pragma unroll
    for (int i = 0; i < 9; i++) {
        int j = t + i * 256;
        if (j < CC) {
            v[i] = __expf(-50.f * fast_tanh((v[i] - mu) * inv_sd));
            es += v[i];
        }
    }
    es = blockReduceSum(es, sm);
    float invz = 1.f / es;
    ushort* wout = CA + (size_t)(b * HWp + m) * CAST;
#pragma unroll
    for (int i = 0; i < 9; i++) {
        int j = t + i * 256;
        if (j < CAST) wout[j] = (j < CC) ? f2bf(v[i] * invz) : (ushort)0;
    }
}

// ---------- Wgt-gather: Wgt[m][q] = sum_s CA[m'_s][j_s] (9-tap, bounds-masked) ----------
// m'_s = (y+1-dy, x+1-dx); j_s = (qy-dy)*46 + (qx-dx). One block per (b,m).
__global__ __launch_bounds__(256) void wgt_gather(const ushort* __restrict__ CA,
                                                  ushort* __restrict__ Wgt) {
    int i0 = blockIdx.x;
    int b = (i0 & 7) >> 1;
    int m = ((i0 >> 3) << 1) | (i0 & 1);
    int y = m / 48, x = m - y * 48;
    const ushort* CAb = CA + (size_t)b * HWp * CAST;
    const ushort* rows[9];
    bool val[9];
#pragma unroll
    for (int dy = 0; dy < 3; dy++)
#pragma unroll
        for (int dx = 0; dx < 3; dx++) {
            int my = y + 1 - dy, mx = x + 1 - dx;
            bool ok = ((unsigned)my < 48u) && ((unsigned)mx < 48u);
            val[dy * 3 + dx] = ok;
            rows[dy * 3 + dx] = CAb + (size_t)(ok ? (my * 48 + mx) : 0) * CAST;
        }
    ushort* out = Wgt + (size_t)(b * HWp + m) * QN;
    int t = threadIdx.x;
#pragma unroll
    for (int i = 0; i < 9; i++) {
        int q = t + i * 256;                 // 2304 = 9*256 exactly
        int qy = q / 48, qx = q - qy * 48;
        float ws = 0.f;
#pragma unroll
        for (int s = 0; s < 9; s++) {
            int dy = s / 3, dx = s % 3;
            int jy = qy - dy, jx = qx - dx;
            if (val[s] && (unsigned)jy < (unsigned)CH && (unsigned)jx < (unsigned)CH)
                ws += bf2f(rows[s][jy * CH + jx]);
        }
        out[q] = f2bf(ws);
    }
}

// ---------- MFMA GEMM core (NT), BK=32, double-buffered (verified R7-R11) ----------
template <int NF, bool NMASK>
__device__ __forceinline__ void gemm_tile_db(const ushort* __restrict__ Ab,
                                             const ushort* __restrict__ Bb,
                                             int lda, int ldb, int kb, int ke,
                                             int Nrem,
                                             ushort* As, ushort* Bs,
                                             float4v (&acc)[4][NF]) {
    constexpr int NBI = (NF + 1) / 2;
    constexpr int BBUF = 2048 * NBI;
    int tid = threadIdx.x;
    int l = tid & 63, w = tid >> 6;
    int quad = l >> 4, l15 = l & 15;
    int sw8 = (l15 >> 1) & 3;
    int wm = (w >> 1) * 64, wn = (w & 1) * (NF * 16);
    int rowInC = l >> 2;
    int cSw = (l & 3) ^ ((l >> 3) & 3);

#pragma unroll
    for (int i = 0; i < 2; i++) {
        int rg = w * 2 + i;
        gld16(Ab + (size_t)(rg * 16 + rowInC) * lda + kb + cSw * 8, As + rg * 512);
    }
#pragma unroll
    for (int i = 0; i < NBI; i++) {
        int rg = w * NBI + i;
        int r = rg * 16 + rowInC;
        if (!NMASK || r < Nrem)
            gld16(Bb + (size_t)r * ldb + kb + cSw * 8, Bs + rg * 512);
    }

    int buf = 0;
    for (int k0 = kb; k0 < ke; k0 += 32) {
        __syncthreads();
        int nb = buf ^ 1;
        if (k0 + 32 < ke) {
#pragma unroll
            for (int i = 0; i < 2; i++) {
                int rg = w * 2 + i;
                gld16(Ab + (size_t)(rg * 16 + rowInC) * lda + (k0 + 32) + cSw * 8,
                      As + nb * 4096 + rg * 512);
            }
#pragma unroll
            for (int i = 0; i < NBI; i++) {
                int rg = w * NBI + i;
                int r = rg * 16 + rowInC;
                if (!NMASK || r < Nrem)
                    gld16(Bb + (size_t)r * ldb + (k0 + 32) + cSw * 8,
                          Bs + nb * BBUF + rg * 512);
            }
        }
        const ushort* Ax = As + buf * 4096;
        const ushort* Bx = Bs + buf * BBUF;
        short8 af[4], bf[NF];
#pragma unroll
        for (int i = 0; i < 4; i++)
            af[i] = *(const short8*)&Ax[(wm + i * 16 + l15) * 32 + ((quad ^ sw8)) * 8];
#pragma unroll
        for (int j = 0; j < NF; j++)
            bf[j] = *(const short8*)&Bx[(wn + j * 16 + l15) * 32 + ((quad ^ sw8)) * 8];
#pragma unroll
        for (int i = 0; i < 4; i++)
#pragma unroll
            for (int j = 0; j < NF; j++)
                acc[i][j] = __builtin_amdgcn_mfma_f32_16x16x32_bf16(af[i], bf[j], acc[i][j], 0, 0, 0);
        buf = nb;
    }
}

// ---------- acl-GEMM: aclP[s][b][m][d] = sum_{q in chunk s} Wgt[m][q]*bgT[d][q] ----------
// 128m x 64n tiles, split-K=8, flat 576-block grid (18 tiles x 4 b x 8 splits).
__global__ __launch_bounds__(256) void acl_gemm(const ushort* __restrict__ Wgt,
                                                const ushort* __restrict__ bgT,
                                                __half* __restrict__ aclP) {
    __shared__ ushort As[2 * 4096];
    __shared__ ushort Bs[2 * 2048];
    int i0 = blockIdx.x;
    int z = i0 & 31;
    int b = z >> 3, split = z & 7;
    int ty = i0 >> 5;                        // 0..17
    int m0 = ty * 128;
    const ushort* Ab = Wgt + (size_t)b * HWp * QN + (size_t)m0 * QN;
    const ushort* Bb = bgT + (size_t)b * DD * QN;
    float4v acc[4][2];
#pragma unroll
    for (int i = 0; i < 4; i++)
#pragma unroll
        for (int j = 0; j < 2; j++) acc[i][j] = (float4v){0.f, 0.f, 0.f, 0.f};

    int kb = split * KCH;
    gemm_tile_db<2, false>(Ab, Bb, QN, QN, kb, kb + KCH, DD, As, Bs, acc);

    int tid = threadIdx.x;
    int lane = tid & 63, wid = tid >> 6;
    int quad = lane >> 4, l15 = lane & 15;
    int wm = (wid >> 1) * 64, wn = (wid & 1) * 32;
    __half* C = aclP + (size_t)(split * BB + b) * HWp * DD;
#pragma unroll
    for (int i = 0; i < 4; i++) {
#pragma unroll
        for (int j = 0; j < 2; j++) {
            int n = wn + j * 16 + l15;       // < 64 always
#pragma unroll
            for (int r = 0; r < 4; r++) {
                int m = m0 + wm + i * 16 + quad * 4 + r;
                C[(size_t)m * DD + n] = __float2half(acc[i][j][r]);
            }
        }
    }
}

// ---------- final: sum 8 split partials, ACL, concat, W2 matmul, ELU ----------
__global__ __launch_bounds__(256) void final_k(const float* __restrict__ g,
                                               const float* __restrict__ mask,
                                               const __half* __restrict__ aclP,
                                               const float* __restrict__ W2,
                                               const float* __restrict__ b2,
                                               float* __restrict__ out) {
    int w = threadIdx.x >> 6, d = threadIdx.x & 63;
    int pix = blockIdx.x * 4 + w;            // b*HWp + m
    int b = pix / HWp, m = pix % HWp;

    __shared__ float con1[4][128];
    float acl = 0.f;
#pragma unroll
    for (int s = 0; s < NSPL; s++)
        acl += __half2float(aclP[((size_t)(s * BB + b) * HWp + m) * DD + d]);
    float mk = mask[pix];
    float gv = g[(size_t)pix * DD + d];
    float bgv = gv * mk;
    float ACL = bgv + (acl / 9.f) * (1.f - mk);
    con1[w][d] = gv;
    con1[w][64 + d] = ACL;
    __syncthreads();
    float accv = b2[d];
#pragma unroll 8
    for (int k = 0; k < 128; k++) accv = fmaf(con1[w][k], W2[k * 64 + d], accv);
    out[(size_t)pix * DD + d] = accv > 0.f ? accv : expm1f(accv);
}

extern "C" void kernel_launch(void* const* d_in, const int* in_sizes, int n_in,
                              void* d_out, int out_size, void* d_ws, size_t ws_size,
                              hipStream_t stream) {
    const float* g    = (const float*)d_in[0];
    const float* mask = (const float*)d_in[1];
    const float* W2   = (const float*)d_in[2];
    const float* b2   = (const float*)d_in[3];
    float* out = (float*)d_out;
    char* ws = (char*)d_ws;

    ushort* gpad  = (ushort*)(ws + OFFB_GPAD);
    ushort* bgpad = (ushort*)(ws + OFFB_BGPAD);
    float*  e     = (float*) (ws + OFFB_E);
    float*  k1d   = (float*) (ws + OFFB_K1D);
    ushort* bgT   = (ushort*)(ws + OFFB_BGT);
    __half* U     = (__half*)(ws + OFFB_U);
    ushort* CA    = (ushort*)(ws + OFFB_CA);
    ushort* Wgt   = (ushort*)(ws + OFFB_WGT);
    __half* aclP  = (__half*)(ws + OFFB_ACLP);

    build_pads<<<BB * PP / 4, 256, 0, stream>>>(g, mask, gpad, bgpad, e);
    build_bgt_k1d<<<144 + 34, 256, 0, stream>>>(bgpad, e, bgT, k1d);

    ugemm<<<dim3(1600), 256, 0, stream>>>(gpad, bgpad, U);

    cs_softmax<<<dim3(8 * 1152), 256, 0, stream>>>(U, k1d, CA);

    wgt_gather<<<dim3(8 * 1152), 256, 0, stream>>>(CA, Wgt);

    acl_gemm<<<dim3(576), 256, 0, stream>>>(Wgt, bgT, aclP);

    final_k<<<BB * HWp / 4, 256, 0, stream>>>(g, mask, aclP, W2, b2, out);
}

// Round 13
// 187.576 us; speedup vs baseline: 1.4396x; 1.4396x over previous
//
#include <hip/hip_runtime.h>
#include <hip/hip_fp16.h>
#include <math.h>

// Problem constants
#define BB 4
#define HH 48
#define WW 48
#define DD 64
#define CH 46
#define CWp 46
#define CC (CH*CWp)      // 2116
#define KK 576           // 9*64
#define HWp (HH*WW)      // 2304
#define KPAD 2176        // 68*32: row stride of S & CA, padded K for GEMM2
#define KSPLIT0 1088     // 34*32; split1 = [1088,2176) = 34 iters
#define PW 50            // zero-padded field width
#define PP (PW*PW)       // 2500 padded pixels

typedef __attribute__((ext_vector_type(8))) short short8;
typedef __attribute__((ext_vector_type(4))) float float4v;

// ---------- workspace layout (byte offsets, all 16B-aligned) ----------
#define OFFB_GPAD  ((size_t)0)            // bf16 [B][2500][64]   1,280,000 B
#define OFFB_BGPAD ((size_t)1280000)      // bf16 [B][2500][64]   1,280,000 B
#define OFFB_E     ((size_t)2560000)      // f32  [B][2304]          36,864 B
#define OFFB_K1D   ((size_t)2596864)      // f32  [B][CC]            33,856 B
#define OFFB_P1T   ((size_t)2630720)      // bf16 [B][576][KPAD] 10,027,008 B
#define OFFB_S     ((size_t)12657728)     // fp16 CS -> bf16 CA [B][HW][KPAD] 40,108,032 B
#define OFFB_AGG0  ((size_t)52765760)     // fp16 [B][HW][576]   10,616,832 B
#define OFFB_AGG1  ((size_t)63382592)     // fp16 [B][HW][576]   10,616,832 B
// total 73,999,424 B

// ---------- helpers ----------
__device__ __forceinline__ ushort f2bf(float x) {
    unsigned u = __float_as_uint(x);
    return (ushort)((u + 0x7FFFu + ((u >> 16) & 1u)) >> 16);
}

__device__ __forceinline__ float waveReduceSum(float x) {
#pragma unroll
    for (int o = 32; o > 0; o >>= 1) x += __shfl_down(x, o, 64);
    return x;
}

__device__ __forceinline__ float blockReduceSum(float x, float* sm) {
#pragma unroll
    for (int o = 32; o > 0; o >>= 1) x += __shfl_down(x, o, 64);
    int lane = threadIdx.x & 63, w = threadIdx.x >> 6;
    __syncthreads();
    if (lane == 0) sm[w] = x;
    __syncthreads();
    return sm[0] + sm[1] + sm[2] + sm[3];
}

// fast tanh via hardware exp: tanh(z) = 1 - 2/(e^{2z}+1)
__device__ __forceinline__ float fast_tanh(float z) {
    float e = __expf(2.f * z);
    return 1.f - 2.f / (e + 1.f);
}

// async 16B global->LDS (wave-uniform LDS base + lane*16)
typedef __attribute__((address_space(3))) void lds_void_t;
typedef __attribute__((address_space(1))) void gmem_void_t;
__device__ __forceinline__ void gld16(const ushort* g, ushort* lds) {
    __builtin_amdgcn_global_load_lds((gmem_void_t*)g, (lds_void_t*)lds, 16, 0, 0);
}

// ---------- build padded fields: gpad = bf16(g), bgpad = bf16(g*mask), e = sum_c bg^2 ----------
__global__ __launch_bounds__(256) void build_pads(const float* __restrict__ g,
                                                  const float* __restrict__ mask,
                                                  ushort* __restrict__ gpad,
                                                  ushort* __restrict__ bgpad,
                                                  float* __restrict__ e) {
    int w = threadIdx.x >> 6, c = threadIdx.x & 63;
    int q4 = blockIdx.x * 4 + w;         // [0, B*2500)
    int b = q4 / PP, q = q4 % PP;
    int yp = q / PW, xp = q % PW;
    size_t o = (size_t)q4 * DD + c;
    if (yp >= 1 && yp <= HH && xp >= 1 && xp <= WW) {
        int pix = (yp - 1) * WW + (xp - 1);
        float gv = g[((size_t)b * HWp + pix) * DD + c];
        float m  = mask[(size_t)b * HWp + pix];
        float bgv = gv * m;
        gpad[o]  = f2bf(gv);
        bgpad[o] = f2bf(bgv);
        float ss = waveReduceSum(bgv * bgv);
        if (c == 0) e[b * HWp + pix] = ss;
    } else {
        gpad[o] = 0;
        bgpad[o] = 0;
    }
}

// ---------- p1t via LDS-tiled transpose from bgpad (+ k1d slice) ----------
__global__ __launch_bounds__(256) void build_p1t(const ushort* __restrict__ bgpad,
                                                 const float* __restrict__ e,
                                                 ushort* __restrict__ p1t,
                                                 float* __restrict__ k1d) {
    int d9 = blockIdx.y, b = blockIdx.z;
    int t = threadIdx.x;
    if (blockIdx.x == 34) {
        int jg = (b * 9 + d9) * 256 + t;
        if (jg < BB * CC) {
            int bb = jg / CC, j = jg % CC;
            int jy = j / CWp, jx = j - jy * CWp;
            const float* eb = e + bb * HWp + jy * WW + jx;
            float s = 0.f;
#pragma unroll
            for (int ddy = 0; ddy < 3; ddy++)
#pragma unroll
                for (int ddx = 0; ddx < 3; ddx++) s += eb[ddy * WW + ddx];
            k1d[jg] = s;
        }
        return;
    }
    __shared__ ushort T[64 * 65];
    int jt = blockIdx.x;
    int dy = d9 / 3, dx = d9 - dy * 3;
    const ushort* src = bgpad + (size_t)b * PP * DD;
    int lr = t >> 3, c8 = (t & 7) * 8;
#pragma unroll
    for (int pass = 0; pass < 2; pass++) {
        int r = lr + pass * 32;
        int j = jt * 64 + r;
        uint4 d = make_uint4(0, 0, 0, 0);
        if (j < CC) {
            int jy = j / CWp, jx = j - jy * CWp;
            d = *(const uint4*)(src + (size_t)((jy + dy + 1) * PW + (jx + dx + 1)) * DD + c8);
        }
        ushort tmp[8];
        *(uint4*)tmp = d;
#pragma unroll
        for (int u = 0; u < 8; u++) T[r * 65 + c8 + u] = tmp[u];
    }
    __syncthreads();
#pragma unroll
    for (int pass = 0; pass < 2; pass++) {
        int c = lr + pass * 32;
        int j8 = (t & 7) * 8;
        ushort tmp[8];
#pragma unroll
        for (int u = 0; u < 8; u++) tmp[u] = T[(j8 + u) * 65 + c];
        *(uint4*)(p1t + ((size_t)b * KK + d9 * 64 + c) * KPAD + jt * 64 + j8) = *(const uint4*)tmp;
    }
}

// ---------- GEMM1: 128x128 tiles (R8-proven best), staged from L2-resident fields ----------
// Flat 1224-block grid; batch = XCD-pair (blkid&7)>>1; per-lane base loop-invariant,
// per-iteration offset wave-uniform. Double-buffered, zero-conflict swizzle.
__global__ __launch_bounds__(256) void gemm1_nt(const ushort* __restrict__ gpad,
                                                const ushort* __restrict__ bgpad,
                                                __half* __restrict__ Cout) {
    __shared__ ushort As[2 * 4096];
    __shared__ ushort Bs[2 * 4096];
    int i0 = blockIdx.x;
    int b = (i0 & 7) >> 1;
    int tile = ((i0 >> 3) << 1) | (i0 & 1);   // 0..305, bijective over 4*306
    int ty = tile / 17, tx = tile - ty * 17;  // 18 m-tiles x 17 n-tiles
    int m0 = ty * 128, n0 = tx * 128;
    const ushort* Ag = gpad + (size_t)b * PP * DD;
    const ushort* Bg = bgpad + (size_t)b * PP * DD;

    int tid = threadIdx.x;
    int l = tid & 63, w = tid >> 6;
    int quad = l >> 4, l15 = l & 15;
    int sw8 = (l15 >> 1) & 3;
    int wm = (w >> 1) * 64, wn = (w & 1) * 64;
    int rowInC = l >> 2;
    int cSw = (l & 3) ^ ((l >> 3) & 3);

    int baseA[2], baseB[2];
    bool vB[2];
#pragma unroll
    for (int i = 0; i < 2; i++) {
        int rg = w * 2 + i;
        int r = rg * 16 + rowInC;
        int p = m0 + r;
        int y = p / WW, x = p - y * WW;
        baseA[i] = (y * PW + x) * DD + cSw * 8;
        int n = n0 + r;
        vB[i] = (n < CC);
        int jy = 0, jx = 0;
        if (vB[i]) { jy = n / CWp; jx = n - jy * CWp; }
        baseB[i] = ((jy + 1) * PW + (jx + 1)) * DD + cSw * 8;
    }

    float4v acc[4][4];
#pragma unroll
    for (int i = 0; i < 4; i++)
#pragma unroll
        for (int j = 0; j < 4; j++) acc[i][j] = (float4v){0.f, 0.f, 0.f, 0.f};

    // prologue: k0 = 0 -> offset 0
#pragma unroll
    for (int i = 0; i < 2; i++) {
        int rg = w * 2 + i;
        gld16(Ag + baseA[i], As + rg * 512);
        if (vB[i]) gld16(Bg + baseB[i], Bs + rg * 512);
    }

    int buf = 0;
    for (int k0 = 0; k0 < KK; k0 += 32) {
        __syncthreads();
        int nb = buf ^ 1;
        int kn = k0 + 32;
        if (kn < KK) {
            int d9 = kn >> 6;
            int dy = d9 / 3, dx = d9 - dy * 3;
            int off = (dy * PW + dx) * DD + (kn & 63);
#pragma unroll
            for (int i = 0; i < 2; i++) {
                int rg = w * 2 + i;
                gld16(Ag + baseA[i] + off, As + nb * 4096 + rg * 512);
                if (vB[i]) gld16(Bg + baseB[i] + off, Bs + nb * 4096 + rg * 512);
            }
        }
        const ushort* Ax = As + buf * 4096;
        const ushort* Bx = Bs + buf * 4096;
        short8 af[4], bf[4];
#pragma unroll
        for (int i = 0; i < 4; i++)
            af[i] = *(const short8*)&Ax[(wm + i * 16 + l15) * 32 + ((quad ^ sw8)) * 8];
#pragma unroll
        for (int j = 0; j < 4; j++)
            bf[j] = *(const short8*)&Bx[(wn + j * 16 + l15) * 32 + ((quad ^ sw8)) * 8];
#pragma unroll
        for (int i = 0; i < 4; i++)
#pragma unroll
            for (int j = 0; j < 4; j++)
                acc[i][j] = __builtin_amdgcn_mfma_f32_16x16x32_bf16(af[i], bf[j], acc[i][j], 0, 0, 0);
        buf = nb;
    }

    __half* C = Cout + (size_t)b * HWp * KPAD;
#pragma unroll
    for (int i = 0; i < 4; i++) {
#pragma unroll
        for (int j = 0; j < 4; j++) {
            int n = n0 + wn + j * 16 + l15;
            if (n < CC) {
#pragma unroll
                for (int r = 0; r < 4; r++) {
                    int m = m0 + wm + i * 16 + quad * 4 + r;
                    C[(size_t)m * KPAD + n] = __float2half(acc[i][j][r]);
                }
            }
        }
    }
}

// ---------- MFMA GEMM core (NT), BK=32, double-buffered (for GEMM2) ----------
template <int NF, bool NMASK>
__device__ __forceinline__ void gemm_tile_db(const ushort* __restrict__ Ab,   // += m0*lda
                                             const ushort* __restrict__ Bb,   // += n0*ldb
                                             int lda, int ldb, int kb, int ke,
                                             int Nrem,
                                             ushort* As, ushort* Bs,
                                             float4v (&acc)[4][NF]) {
    constexpr int NBI = NF / 2;
    constexpr int BBUF = 2048 * NBI;          // ushorts per B buffer
    int tid = threadIdx.x;
    int l = tid & 63, w = tid >> 6;
    int quad = l >> 4, l15 = l & 15;
    int sw8 = (l15 >> 1) & 3;
    int wm = (w >> 1) * 64, wn = (w & 1) * (NF * 16);
    int rowInC = l >> 2;
    int cSw = (l & 3) ^ ((l >> 3) & 3);

#pragma unroll
    for (int i = 0; i < 2; i++) {
        int rg = w * 2 + i;
        gld16(Ab + (size_t)(rg * 16 + rowInC) * lda + kb + cSw * 8, As + rg * 512);
    }
#pragma unroll
    for (int i = 0; i < NBI; i++) {
        int rg = w * NBI + i;
        int r = rg * 16 + rowInC;
        if (!NMASK || r < Nrem)
            gld16(Bb + (size_t)r * ldb + kb + cSw * 8, Bs + rg * 512);
    }

    int buf = 0;
    for (int k0 = kb; k0 < ke; k0 += 32) {
        __syncthreads();
        int nb = buf ^ 1;
        if (k0 + 32 < ke) {
#pragma unroll
            for (int i = 0; i < 2; i++) {
                int rg = w * 2 + i;
                gld16(Ab + (size_t)(rg * 16 + rowInC) * lda + (k0 + 32) + cSw * 8,
                      As + nb * 4096 + rg * 512);
            }
#pragma unroll
            for (int i = 0; i < NBI; i++) {
                int rg = w * NBI + i;
                int r = rg * 16 + rowInC;
                if (!NMASK || r < Nrem)
                    gld16(Bb + (size_t)r * ldb + (k0 + 32) + cSw * 8,
                          Bs + nb * BBUF + rg * 512);
            }
        }
        const ushort* Ax = As + buf * 4096;
        const ushort* Bx = Bs + buf * BBUF;
        short8 af[4], bf[NF];
#pragma unroll
        for (int i = 0; i < 4; i++)
            af[i] = *(const short8*)&Ax[(wm + i * 16 + l15) * 32 + ((quad ^ sw8)) * 8];
#pragma unroll
        for (int j = 0; j < NF; j++)
            bf[j] = *(const short8*)&Bx[(wn + j * 16 + l15) * 32 + ((quad ^ sw8)) * 8];
#pragma unroll
        for (int i = 0; i < 4; i++)
#pragma unroll
            for (int j = 0; j < NF; j++)
                acc[i][j] = __builtin_amdgcn_mfma_f32_16x16x32_bf16(af[i], bf[j], acc[i][j], 0, 0, 0);
        buf = nb;
    }
}

// ---------- GEMM2 split-K=2: 128m x 192n tiles, fp16 partials ----------
// Flat 432-block grid; z-slice = blkid&7 pins (batch,split) per XCD.
__global__ __launch_bounds__(256) void gemm2_split(const ushort* __restrict__ A,
                                                   const ushort* __restrict__ Bt,
                                                   __half* __restrict__ agg0,
                                                   __half* __restrict__ agg1) {
    __shared__ ushort As[2 * 4096];
    __shared__ ushort Bs[2 * 6144];
    int i0 = blockIdx.x;
    int z = i0 & 7;
    int b = z >> 1, split = z & 1;
    int tile = i0 >> 3;                      // 0..53
    int ty = tile / 3, tx = tile - ty * 3;   // 18 m-tiles x 3 n-tiles
    int m0 = ty * 128, n0 = tx * 192;
    const ushort* Ab = A + (size_t)b * HWp * KPAD + (size_t)m0 * KPAD;
    const ushort* Bb = Bt + (size_t)b * KK * KPAD + (size_t)n0 * KPAD;
    float4v acc[4][6];
#pragma unroll
    for (int i = 0; i < 4; i++)
#pragma unroll
        for (int j = 0; j < 6; j++) acc[i][j] = (float4v){0.f, 0.f, 0.f, 0.f};

    gemm_tile_db<6, false>(Ab, Bb, KPAD, KPAD, split ? KSPLIT0 : 0,
                           split ? KPAD : KSPLIT0, 192, As, Bs, acc);

    int tid = threadIdx.x;
    int lane = tid & 63, wid = tid >> 6;
    int quad = lane >> 4, l15 = lane & 15;
    int wm = (wid >> 1) * 64, wn = (wid & 1) * 96;
    __half* C = (split ? agg1 : agg0) + (size_t)b * HWp * KK;
#pragma unroll
    for (int i = 0; i < 4; i++) {
#pragma unroll
        for (int j = 0; j < 6; j++) {
            int n = n0 + wn + j * 16 + l15;
#pragma unroll
            for (int r = 0; r < 4; r++) {
                int m = m0 + wm + i * 16 + quad * 4 + r;
                C[(size_t)m * KK + n] = __float2half(acc[i][j][r]);
            }
        }
    }
}

// ---------- row-wise: DS1 = k1d[n]-2*CS; standardize; -50*tanh; softmax; bf16 CA ----------
__global__ __launch_bounds__(256) void rowsoft(void* __restrict__ Sbase,
                                               const float* __restrict__ k1d) {
    __shared__ float sm[4];
    size_t row = blockIdx.x;
    int b = (int)(row / HWp);
    const __half* p = (const __half*)Sbase + row * KPAD;
    ushort* wout = (ushort*)Sbase + row * KPAD;
    const float* k1 = k1d + (size_t)b * CC;
    int t = threadIdx.x;
    bool hasx = t < 34;

    uint4 raw = *(const uint4*)(p + t * 8);
    uint rx = hasx ? *(const uint*)(p + 2048 + t * 2) : 0u;
    float v[8], vx[2];
    {
        const __half2* h2 = (const __half2*)&raw;
#pragma unroll
        for (int i = 0; i < 4; i++) {
            float2 f = __half22float2(h2[i]);
            v[2 * i] = f.x; v[2 * i + 1] = f.y;
        }
        __half2 hx = *(__half2*)&rx;
        float2 fx = __half22float2(hx);
        vx[0] = fx.x; vx[1] = fx.y;
    }
    {
        const float* kp = k1 + t * 8;
#pragma unroll
        for (int i = 0; i < 8; i++) v[i] = kp[i] - 2.f * v[i];
        if (hasx) {
            vx[0] = k1[2048 + t * 2] - 2.f * vx[0];
            vx[1] = k1[2048 + t * 2 + 1] - 2.f * vx[1];
        }
    }
    float s = 0.f;
#pragma unroll
    for (int i = 0; i < 8; i++) s += v[i];
    if (hasx) s += vx[0] + vx[1];
    s = blockReduceSum(s, sm);
    float mu = s / (float)CC;
    float vs = 0.f;
#pragma unroll
    for (int i = 0; i < 8; i++) { float d = v[i] - mu; vs += d * d; }
    if (hasx) { float d0 = vx[0] - mu, d1 = vx[1] - mu; vs += d0 * d0 + d1 * d1; }
    vs = blockReduceSum(vs, sm);
    float inv_sd = 1.f / sqrtf(vs / (float)CC);
    float es = 0.f;
#pragma unroll
    for (int i = 0; i < 8; i++) {
        v[i] = __expf(-50.f * fast_tanh((v[i] - mu) * inv_sd));
        es += v[i];
    }
    if (hasx) {
        vx[0] = __expf(-50.f * fast_tanh((vx[0] - mu) * inv_sd));
        vx[1] = __expf(-50.f * fast_tanh((vx[1] - mu) * inv_sd));
        es += vx[0] + vx[1];
    }
    es = blockReduceSum(es, sm);
    float invz = 1.f / es;

    ushort o[8];
#pragma unroll
    for (int i = 0; i < 8; i++) o[i] = f2bf(v[i] * invz);
    *(uint4*)(wout + t * 8) = *(const uint4*)o;
    if (hasx) {
        ushort ox[2] = { f2bf(vx[0] * invz), f2bf(vx[1] * invz) };
        *(uint*)(wout + 2048 + t * 2) = *(const uint*)ox;
    } else {
        *(uint*)(wout + CC + 2 * (t - 34)) = 0u;
    }
}

// ---------- final: sum 2 split partials, 9-shift combine, ACL, concat, W2, ELU ----------
__global__ __launch_bounds__(256) void final_k(const float* __restrict__ g,
                                               const float* __restrict__ mask,
                                               const __half* __restrict__ agg0,
                                               const __half* __restrict__ agg1,
                                               const float* __restrict__ W2,
                                               const float* __restrict__ b2,
                                               float* __restrict__ out) {
    int w = threadIdx.x >> 6, d = threadIdx.x & 63;
    int pix = blockIdx.x * 4 + w;
    int b = pix / HWp, yx = pix % HWp;
    int y = yx / WW, x = yx % WW;

    __shared__ float con1[4][128];
    float acl = 0.f;
#pragma unroll
    for (int dy = 0; dy < 3; dy++) {
#pragma unroll
        for (int dx = 0; dx < 3; dx++) {
            int yy = y + 1 - dy, xx = x + 1 - dx;
            if (yy >= 0 && yy < HH && xx >= 0 && xx < WW) {
                size_t off = ((size_t)(b * HWp + yy * WW + xx)) * KK + (dy * 3 + dx) * DD + d;
                acl += __half2float(agg0[off]) + __half2float(agg1[off]);
            }
        }
    }
    float m = mask[pix];
    float gv = g[(size_t)pix * DD + d];
    float bgv = gv * m;
    float ACL = bgv + (acl / 9.f) * (1.f - m);
    con1[w][d] = gv;
    con1[w][64 + d] = ACL;
    __syncthreads();
    float accv = b2[d];
#pragma unroll 8
    for (int k = 0; k < 128; k++) accv = fmaf(con1[w][k], W2[k * 64 + d], accv);
    out[(size_t)pix * DD + d] = accv > 0.f ? accv : expm1f(accv);
}

extern "C" void kernel_launch(void* const* d_in, const int* in_sizes, int n_in,
                              void* d_out, int out_size, void* d_ws, size_t ws_size,
                              hipStream_t stream) {
    const float* g    = (const float*)d_in[0];
    const float* mask = (const float*)d_in[1];
    const float* W2   = (const float*)d_in[2];
    const float* b2   = (const float*)d_in[3];
    float* out = (float*)d_out;
    char* ws = (char*)d_ws;

    ushort* gpad  = (ushort*)(ws + OFFB_GPAD);
    ushort* bgpad = (ushort*)(ws + OFFB_BGPAD);
    float*  e     = (float*) (ws + OFFB_E);
    float*  k1d   = (float*) (ws + OFFB_K1D);
    ushort* p1t   = (ushort*)(ws + OFFB_P1T);
    void*   S     = (void*)  (ws + OFFB_S);     // fp16 CS, then bf16 CA in place
    __half* agg0  = (__half*)(ws + OFFB_AGG0);
    __half* agg1  = (__half*)(ws + OFFB_AGG1);

    build_pads<<<BB * PP / 4, 256, 0, stream>>>(g, mask, gpad, bgpad, e);
    build_p1t<<<dim3(35, 9, BB), 256, 0, stream>>>(bgpad, e, p1t, k1d);

    gemm1_nt<<<dim3(1224), 256, 0, stream>>>(gpad, bgpad, (__half*)S);

    rowsoft<<<BB * HWp, 256, 0, stream>>>(S, k1d);

    gemm2_split<<<dim3(432), 256, 0, stream>>>((const ushort*)S, p1t, agg0, agg1);

    final_k<<<BB * HWp / 4, 256, 0, stream>>>(g, mask, agg0, agg1, W2, b2, out);
}